// Round 5
// baseline (203.510 us; speedup 1.0000x reference)
//
#include <hip/hip_runtime.h>
#include <hip/hip_bf16.h>

// Shapes: b=2,t=8,l=1024,c=256,h=8,d=32 -> NTOK=16384, BTH=128
// Inputs/outputs: float32. ws intermediates: _Float16.
// ws layout (f16): qn | kn | vt | xa, each 4194304 elems (8MB) -> 32MB
//   qn/kn/xa: [bth][l][32]; vt TRANSPOSED: [bth][32][l] with the k (column)
//   index bit-permuted (bits 2<->3 swapped within each 16-block) so that a
//   plain f16x8 load yields the PV A-fragment matching P's natural register
//   order after the swapped 32x32 QK^T (no P transpose needed at all).
//   W-f16 scratch (Wq|Wk|Wv, 3*65536) aliases the xa region: it is consumed
//   by proj_mfma before attn overwrites xa. Stream order guarantees safety.
// qn is pre-scaled by log2(e)/sqrt(32) so attn uses exp2 directly.

#define NTOK  16384
#define CDIM  256
#define LSEQ  1024
#define HEADS 8
#define DHEAD 32

typedef _Float16 f16;
typedef __attribute__((ext_vector_type(2))) _Float16 f16x2;
typedef __attribute__((ext_vector_type(4))) _Float16 f16x4;
typedef __attribute__((ext_vector_type(8))) _Float16 f16x8;
typedef __attribute__((ext_vector_type(4))) float f32x4;
typedef __attribute__((ext_vector_type(16))) float f32x16;

#define QSCALE (0.17677669529663687f * 1.4426950408889634f)  // 1/sqrt(32)*log2e

__device__ __forceinline__ f16x2 pkcvt(float a, float b) {
  auto r = __builtin_amdgcn_cvt_pkrtz(a, b);  // v_cvt_pkrtz_f16_f32
  union { decltype(r) in; f16x2 out; } u;
  u.in = r;
  return u.out;
}

// pack two pre-loaded float4s -> f16x8 fragment (no loads inside!)
__device__ __forceinline__ f16x8 pack8(float4 a, float4 b) {
  union { f16x8 v; f16x2 h[4]; } u;
  u.h[0] = pkcvt(a.x, a.y);
  u.h[1] = pkcvt(a.z, a.w);
  u.h[2] = pkcvt(b.x, b.y);
  u.h[3] = pkcvt(b.z, b.w);
  return u.v;
}

// ---------------------------------------------------------------------------
// Kernel 0: convert Wq|Wk|Wv (each 256x256 f32) to f16, packed consecutively.
// ---------------------------------------------------------------------------
__global__ __launch_bounds__(256)
void cvt_w_kernel(const float* __restrict__ Wq, const float* __restrict__ Wk,
                  const float* __restrict__ Wv, f16* __restrict__ dst) {
  const int m = blockIdx.x >> 6;  // matrix index
  const float* src = (m == 0) ? Wq : (m == 1) ? Wk : Wv;
  const int base = (blockIdx.x & 63) * 1024 + threadIdx.x * 4;
  float4 a = *(const float4*)(src + base);
  union { f16x4 v; f16x2 h[2]; } u;
  u.h[0] = pkcvt(a.x, a.y);
  u.h[1] = pkcvt(a.z, a.w);
  *(f16x4*)(dst + m * 65536 + base) = u.v;
}

// ---------------------------------------------------------------------------
// Kernel 1: fused Q/K/V projection + bias + per-head L2-norm via MFMA.
// Round 5: latency fix. (a) 32 tokens/block -> grid (512,3), 6 blocks/CU
// available (was 3) for 2x TLP. (b) Per k-step, ALL global loads issue into
// named registers BEFORE any cvt/MFMA consumes them -> one amortized
// vmcnt wait instead of 12 serialized load->use chains (round-4 counters:
// 14.5k cyc/iter vs ~150 compute = serialized HBM latency).
// Wave w: out-channels 64w..64w+63 (heads 2w,2w+1) x 32 tokens.
// C-layout: col=l16 -> token, row=quad*4+r -> och.
// V store: transposed [32][LSEQ] with column bits 2<->3 swapped (see header).
// ---------------------------------------------------------------------------
__global__ __launch_bounds__(256, 4)
void proj_mfma_kernel(const float* __restrict__ xq, const float* __restrict__ xk,
                      const float* __restrict__ xv, const f16* __restrict__ w16,
                      const float* __restrict__ bq, const float* __restrict__ bk,
                      const float* __restrict__ bv,
                      f16* __restrict__ qn, f16* __restrict__ kn,
                      f16* __restrict__ vt) {
  const int which = blockIdx.y;
  const float* x    = (which == 0) ? xq : (which == 1) ? xk : xv;
  const float* bias = (which == 0) ? bq : (which == 1) ? bk : bv;
  const f16* W      = w16 + which * 65536;
  f16* out          = (which == 0) ? qn : (which == 1) ? kn : vt;
  const float scale = (which == 0) ? QSCALE : 1.0f;
  const bool transposed = (which == 2);

  const int tid = threadIdx.x;
  const int wave = tid >> 6, lane = tid & 63;
  const int quad = lane >> 4, l16 = lane & 15;
  const int tokbase = blockIdx.x * 32;
  const int wbase = wave * 64;

  f32x4 acc[4][2];  // [m-tile][n-tile]
#pragma unroll
  for (int mt = 0; mt < 4; ++mt)
#pragma unroll
    for (int nt = 0; nt < 2; ++nt) acc[mt][nt] = (f32x4){0.f, 0.f, 0.f, 0.f};

#pragma unroll
  for (int kk = 0; kk < 8; ++kk) {
    // ---- batched loads: 4x f16x8 (W) + 4x float4 (x), no consumer between
    f16x8 af[4];
#pragma unroll
    for (int mt = 0; mt < 4; ++mt)
      af[mt] = *(const f16x8*)(W + (size_t)(wbase + mt * 16 + l16) * CDIM +
                               kk * 32 + quad * 8);
    const float* xr0 = x + (size_t)(tokbase + l16) * CDIM + kk * 32 + quad * 8;
    const float* xr1 = x + (size_t)(tokbase + 16 + l16) * CDIM + kk * 32 + quad * 8;
    float4 xa0 = *(const float4*)xr0;
    float4 xb0 = *(const float4*)(xr0 + 4);
    float4 xa1 = *(const float4*)xr1;
    float4 xb1 = *(const float4*)(xr1 + 4);
    // ---- convert ----
    f16x8 bf0 = pack8(xa0, xb0);
    f16x8 bf1 = pack8(xa1, xb1);
    // ---- MFMAs ----
#pragma unroll
    for (int mt = 0; mt < 4; ++mt) {
      acc[mt][0] = __builtin_amdgcn_mfma_f32_16x16x32_f16(af[mt], bf0,
                                                          acc[mt][0], 0, 0, 0);
      acc[mt][1] = __builtin_amdgcn_mfma_f32_16x16x32_f16(af[mt], bf1,
                                                          acc[mt][1], 0, 0, 0);
    }
  }

  // epilogue: bias -> per-head L2 norm (d spans 2 m-tiles x 4 quads) -> store
  const int bt = tokbase >> 10, l0 = tokbase & 1023;
#pragma unroll
  for (int hh = 0; hh < 2; ++hh) {
    const int h = wave * 2 + hh;
    const size_t hb = (size_t)(bt * HEADS + h) * (LSEQ * DHEAD);
    float4 b0 = *(const float4*)(bias + wbase + hh * 32 + quad * 4);
    float4 b1 = *(const float4*)(bias + wbase + hh * 32 + 16 + quad * 4);
#pragma unroll
    for (int nt = 0; nt < 2; ++nt) {
      f32x4 a0 = acc[hh * 2 + 0][nt];
      f32x4 a1 = acc[hh * 2 + 1][nt];
      float v0[4], v1[4];
      v0[0] = a0[0] + b0.x; v0[1] = a0[1] + b0.y;
      v0[2] = a0[2] + b0.z; v0[3] = a0[3] + b0.w;
      v1[0] = a1[0] + b1.x; v1[1] = a1[1] + b1.y;
      v1[2] = a1[2] + b1.z; v1[3] = a1[3] + b1.w;
      float ss = 0.f;
#pragma unroll
      for (int r = 0; r < 4; ++r) ss += v0[r] * v0[r] + v1[r] * v1[r];
      ss += __shfl_xor(ss, 16);
      ss += __shfl_xor(ss, 32);
      const float inv = scale / fmaxf(sqrtf(ss), 1e-12f);
      const int tok_l = l0 + nt * 16 + l16;
      if (!transposed) {
        f16x4 o0, o1;
#pragma unroll
        for (int r = 0; r < 4; ++r) {
          o0[r] = (f16)(v0[r] * inv);
          o1[r] = (f16)(v1[r] * inv);
        }
        *(f16x4*)(out + hb + (size_t)tok_l * DHEAD + quad * 4) = o0;
        *(f16x4*)(out + hb + (size_t)tok_l * DHEAD + 16 + quad * 4) = o1;
      } else {
        // column index with bits 2<->3 swapped (within each 16-token block):
        // memory[col] holds token f(col); f is an involution.
        const int tcol = (tok_l & ~12) | ((tok_l & 4) << 1) | ((tok_l & 8) >> 1);
#pragma unroll
        for (int r = 0; r < 4; ++r) {
          out[hb + (size_t)(quad * 4 + r) * LSEQ + tcol] = (f16)(v0[r] * inv);
          out[hb + (size_t)(16 + quad * 4 + r) * LSEQ + tcol] = (f16)(v1[r] * inv);
        }
      }
    }
  }
}

// ---------------------------------------------------------------------------
// Kernel 2: attention via swapped 32x32x16 MFMA. (unchanged from round 4 —
// verified: LDS-staged K/V shared by 4 waves, double-buffered; attn fell
// from 53.6us out of the top-5.)
// ---------------------------------------------------------------------------
#define TKROW 40  // padded K row, f16 units (64 rows/tile)
#define TVROW 72  // padded V row, f16 units (32 rows, 64 k-cols/tile)

__global__ __launch_bounds__(256, 4)
void attn_mfma_kernel(const f16* __restrict__ qn,
                      const f16* __restrict__ kn,
                      const f16* __restrict__ vt,
                      f16* __restrict__ xo) {
  __shared__ f16 kl[2][64 * TKROW];  // 2 x 5120B
  __shared__ f16 vl[2][32 * TVROW];  // 2 x 4608B
  const int tid  = threadIdx.x;
  const int wave = tid >> 6, lane = tid & 63;
  const int l32 = lane & 31, hi = lane >> 5;
  // XCD-aware swizzle: all 8 q-chunk blocks of a head land on one XCD's L2.
  const int wid = (blockIdx.x & 7) * 128 + (blockIdx.x >> 3);
  const int bth = wid >> 3;
  const int qbase = ((wid & 7) << 7) + wave * 32;
  const size_t hb = (size_t)bth * (LSEQ * DHEAD);

  const f16* qp = qn + hb + (size_t)(qbase + l32) * DHEAD + hi * 8;
  const f16x8 qf0 = *(const f16x8*)qp;
  const f16x8 qf1 = *(const f16x8*)(qp + 16);

  // staging split: wave w stages K rows 16w..16w+15 (4 lanes/row, 16B chunks)
  // and V rows 8w..8w+7 (8 lanes/row, 16B chunks). Dense 1KB per wave-load.
  const int krow_w = wave * 16 + (lane >> 2), kcol = (lane & 3) * 8;
  const int vrow_w = wave * 8 + (lane >> 3), vcol = (lane & 7) * 8;
  const f16* gK = kn + hb + (size_t)krow_w * DHEAD + kcol;  // + t*64*DHEAD
  const f16* gV = vt + hb + (size_t)vrow_w * LSEQ + vcol;   // + t*64
  const int lK = krow_w * TKROW + kcol;
  const int lV = vrow_w * TVROW + vcol;

  f32x16 oacc, z16;
#pragma unroll
  for (int r = 0; r < 16; ++r) { oacc[r] = 0.f; z16[r] = 0.f; }
  float ls0 = 0.f, ls1 = 0.f;

#define EXPPV(s, v0, v1) { \
    union { f16x8 v; f16x2 h[4]; } _q0, _q1; \
    _Pragma("unroll") \
    for (int i = 0; i < 4; ++i) { \
      float e0 = __builtin_amdgcn_exp2f(s[2 * i]); \
      float e1 = __builtin_amdgcn_exp2f(s[2 * i + 1]); \
      ls0 += e0; ls1 += e1; \
      _q0.h[i] = pkcvt(e0, e1); \
      float e2 = __builtin_amdgcn_exp2f(s[8 + 2 * i]); \
      float e3 = __builtin_amdgcn_exp2f(s[9 + 2 * i]); \
      ls0 += e2; ls1 += e3; \
      _q1.h[i] = pkcvt(e2, e3); \
    } \
    oacc = __builtin_amdgcn_mfma_f32_32x32x16_f16(v0, _q0.v, oacc, 0, 0, 0); \
    oacc = __builtin_amdgcn_mfma_f32_32x32x16_f16(v1, _q1.v, oacc, 0, 0, 0); }

  // prologue: stage tile 0, issue tile 1 loads
  f16x8 gk = *(const f16x8*)gK;
  f16x8 gv = *(const f16x8*)gV;
  *(f16x8*)(&kl[0][lK]) = gk;
  *(f16x8*)(&vl[0][lV]) = gv;
  gk = *(const f16x8*)(gK + 64 * DHEAD);
  gv = *(const f16x8*)(gV + 64);
  __syncthreads();

  for (int t = 0; t < 16; ++t) {
    const f16* kb = kl[t & 1];
    const f16* vb = vl[t & 1];
#pragma unroll
    for (int sub = 0; sub < 2; ++sub) {
      f16x8 kf0 = *(const f16x8*)(kb + (sub * 32 + l32) * TKROW + hi * 8);
      f16x8 kf1 = *(const f16x8*)(kb + (sub * 32 + l32) * TKROW + hi * 8 + 16);
      f16x8 vf0 = *(const f16x8*)(vb + l32 * TVROW + sub * 32 + hi * 8);
      f16x8 vf1 = *(const f16x8*)(vb + l32 * TVROW + sub * 32 + hi * 8 + 16);
      f32x16 s = __builtin_amdgcn_mfma_f32_32x32x16_f16(kf0, qf0, z16, 0, 0, 0);
      s = __builtin_amdgcn_mfma_f32_32x32x16_f16(kf1, qf1, s, 0, 0, 0);
      EXPPV(s, vf0, vf1)
    }
    if (t < 15) {
      __syncthreads();  // all waves done reading buf[(t+1)&1] (tile t-1)
      *(f16x8*)(&kl[(t + 1) & 1][lK]) = gk;
      *(f16x8*)(&vl[(t + 1) & 1][lV]) = gv;
      if (t + 1 < 15) {  // issue tile t+2: covered by tile t+1's compute
        gk = *(const f16x8*)(gK + (size_t)(t + 2) * 64 * DHEAD);
        gv = *(const f16x8*)(gV + (t + 2) * 64);
      }
      __syncthreads();  // buf[(t+1)&1] visible
    }
  }
#undef EXPPV

  float lsum = ls0 + ls1;        // own 16 k-rows
  lsum += __shfl_xor(lsum, 32);  // + partner half's 16 k-rows
  const float inv = __builtin_amdgcn_rcpf(lsum);

  f16* op = xo + hb + (size_t)(qbase + l32) * DHEAD + hi * 4;
#pragma unroll
  for (int g = 0; g < 4; ++g) {   // d-base = 8g + 4hi, 4 contiguous d each
    union { f16x4 v; f16x2 h[2]; } o;
    o.h[0] = pkcvt(oacc[4 * g + 0] * inv, oacc[4 * g + 1] * inv);
    o.h[1] = pkcvt(oacc[4 * g + 2] * inv, oacc[4 * g + 3] * inv);
    *(f16x4*)(op + 8 * g) = o.v;
  }
}

// ---------------------------------------------------------------------------
// Kernel 3: out = xatt @ Wm^T + bm + residual, f32 out, via MFMA.
// Round 5: same latency fix as proj — 32 tokens/block (grid 512, was 256 =
// 1 block/CU = 1 wave/SIMD!), batched loads (8x float4 Wm + 2x f16x8 xatt
// issue before any cvt), then convert, then MFMAs.
// ---------------------------------------------------------------------------
__global__ __launch_bounds__(256, 4)
void out_proj_mfma_kernel(const f16* __restrict__ xatt,
                          const float* __restrict__ Wm,
                          const float* __restrict__ bm,
                          const float* __restrict__ resid,
                          float* __restrict__ out) {
  const int tid = threadIdx.x;
  const int wave = tid >> 6, lane = tid & 63;
  const int quad = lane >> 4, l16 = lane & 15;
  const int tokbase = blockIdx.x * 32;
  const int wbase = wave * 64;
  const int bt = tokbase >> 10, l0 = tokbase & 1023;

  f32x4 acc[4][2];
#pragma unroll
  for (int mt = 0; mt < 4; ++mt)
#pragma unroll
    for (int nt = 0; nt < 2; ++nt) acc[mt][nt] = (f32x4){0.f, 0.f, 0.f, 0.f};

#pragma unroll
  for (int kk = 0; kk < 8; ++kk) {
    const size_t hbk = (size_t)(bt * HEADS + kk) * (LSEQ * DHEAD);
    // ---- batched loads: 8x float4 (Wm) + 2x f16x8 (xatt) ----
    const float* w0 = Wm + (size_t)(wbase + 0 * 16 + l16) * CDIM + kk * 32 + quad * 8;
    const float* w1 = Wm + (size_t)(wbase + 1 * 16 + l16) * CDIM + kk * 32 + quad * 8;
    const float* w2 = Wm + (size_t)(wbase + 2 * 16 + l16) * CDIM + kk * 32 + quad * 8;
    const float* w3 = Wm + (size_t)(wbase + 3 * 16 + l16) * CDIM + kk * 32 + quad * 8;
    float4 wa0 = *(const float4*)w0, wb0 = *(const float4*)(w0 + 4);
    float4 wa1 = *(const float4*)w1, wb1 = *(const float4*)(w1 + 4);
    float4 wa2 = *(const float4*)w2, wb2 = *(const float4*)(w2 + 4);
    float4 wa3 = *(const float4*)w3, wb3 = *(const float4*)(w3 + 4);
    f16x8 bf0 = *(const f16x8*)(xatt + hbk + (size_t)(l0 + l16) * DHEAD + quad * 8);
    f16x8 bf1 = *(const f16x8*)(xatt + hbk + (size_t)(l0 + 16 + l16) * DHEAD + quad * 8);
    // ---- convert ----
    f16x8 af0 = pack8(wa0, wb0);
    f16x8 af1 = pack8(wa1, wb1);
    f16x8 af2 = pack8(wa2, wb2);
    f16x8 af3 = pack8(wa3, wb3);
    // ---- MFMAs ----
    acc[0][0] = __builtin_amdgcn_mfma_f32_16x16x32_f16(af0, bf0, acc[0][0], 0, 0, 0);
    acc[0][1] = __builtin_amdgcn_mfma_f32_16x16x32_f16(af0, bf1, acc[0][1], 0, 0, 0);
    acc[1][0] = __builtin_amdgcn_mfma_f32_16x16x32_f16(af1, bf0, acc[1][0], 0, 0, 0);
    acc[1][1] = __builtin_amdgcn_mfma_f32_16x16x32_f16(af1, bf1, acc[1][1], 0, 0, 0);
    acc[2][0] = __builtin_amdgcn_mfma_f32_16x16x32_f16(af2, bf0, acc[2][0], 0, 0, 0);
    acc[2][1] = __builtin_amdgcn_mfma_f32_16x16x32_f16(af2, bf1, acc[2][1], 0, 0, 0);
    acc[3][0] = __builtin_amdgcn_mfma_f32_16x16x32_f16(af3, bf0, acc[3][0], 0, 0, 0);
    acc[3][1] = __builtin_amdgcn_mfma_f32_16x16x32_f16(af3, bf1, acc[3][1], 0, 0, 0);
  }

#pragma unroll
  for (int mt = 0; mt < 4; ++mt) {
    float4 bv = *(const float4*)(bm + wbase + mt * 16 + quad * 4);
#pragma unroll
    for (int nt = 0; nt < 2; ++nt) {
      const int tok = tokbase + nt * 16 + l16;
      const size_t off = (size_t)tok * CDIM + wbase + mt * 16 + quad * 4;
      float4 rv = *(const float4*)(resid + off);
      float4 o;
      o.x = acc[mt][nt][0] + bv.x + rv.x;
      o.y = acc[mt][nt][1] + bv.y + rv.y;
      o.z = acc[mt][nt][2] + bv.z + rv.z;
      o.w = acc[mt][nt][3] + bv.w + rv.w;
      *(float4*)(out + off) = o;
    }
  }
}

extern "C" void kernel_launch(void* const* d_in, const int* in_sizes, int n_in,
                              void* d_out, int out_size, void* d_ws,
                              size_t ws_size, hipStream_t stream) {
  const float* q  = (const float*)d_in[0];
  const float* k  = (const float*)d_in[1];
  const float* v  = (const float*)d_in[2];
  const float* Wq = (const float*)d_in[3];
  const float* bq = (const float*)d_in[4];
  const float* Wk = (const float*)d_in[5];
  const float* bk = (const float*)d_in[6];
  const float* Wv = (const float*)d_in[7];
  const float* bv = (const float*)d_in[8];
  const float* Wm = (const float*)d_in[9];
  const float* bm = (const float*)d_in[10];
  float* outp = (float*)d_out;

  f16* ws = (f16*)d_ws;
  const size_t TENS = (size_t)NTOK * CDIM;  // 4194304
  f16* qn  = ws;
  f16* kn  = ws + TENS;
  f16* vt  = ws + 2 * TENS;
  f16* xa  = ws + 3 * TENS;
  f16* w16 = xa;  // alias: consumed by proj_mfma before attn writes xa

  dim3 blk(256);
  cvt_w_kernel<<<dim3(192), blk, 0, stream>>>(Wq, Wk, Wv, w16);
  proj_mfma_kernel<<<dim3(512, 3), blk, 0, stream>>>(q, k, v, w16, bq, bk, bv,
                                                     qn, kn, vt);
  attn_mfma_kernel<<<dim3(1024), blk, 0, stream>>>(qn, kn, vt, xa);
  out_proj_mfma_kernel<<<dim3(512), blk, 0, stream>>>(xa, Wm, bm, q, outp);
}

// Round 6
// 156.563 us; speedup vs baseline: 1.2999x; 1.2999x over previous
//
#include <hip/hip_runtime.h>
#include <hip/hip_bf16.h>

// Shapes: b=2,t=8,l=1024,c=256,h=8,d=32 -> NTOK=16384, BTH=128
// Inputs/outputs: float32. ws intermediates: _Float16.
// ws layout (f16): qn | kn | vt (each 4194304 elems, 24MB) | w16 (4x65536,
//   512KB, k-major tiled [kk][och][32] for Wq,Wk,Wv,Wm).
//   xa ALIASES qn: attn reads its q-rows at kernel start and writes its
//   output to exactly those rows at the end; row ranges are disjoint across
//   blocks, so the alias is race-free. This keeps w16 (incl. Wm) alive for
//   out_proj.
//   vt TRANSPOSED: [bth][32][l] with the k (column) index bit-permuted
//   (bits 2<->3 swapped within each 16-block) so a plain f16x8 load yields
//   the PV A-fragment matching P's register order after swapped QK^T.
// qn is pre-scaled by log2(e)/sqrt(32) so attn uses exp2 directly.
//
// Round 6 theory: every kernel was limited by vector-memory LINE throughput
// (strided 16B loads touching 16-32 lines/instr; TA-bound, both pipes idle).
// Fix: k-major W tiles (dense 1KB A-frag loads) + LDS-staged B-operands with
// dense global reads, reusing attn's proven conflict-free 40-f16-row LDS
// geometry.

#define NTOK  16384
#define CDIM  256
#define LSEQ  1024
#define HEADS 8
#define DHEAD 32

typedef _Float16 f16;
typedef __attribute__((ext_vector_type(2))) _Float16 f16x2;
typedef __attribute__((ext_vector_type(4))) _Float16 f16x4;
typedef __attribute__((ext_vector_type(8))) _Float16 f16x8;
typedef __attribute__((ext_vector_type(4))) float f32x4;
typedef __attribute__((ext_vector_type(16))) float f32x16;

#define QSCALE (0.17677669529663687f * 1.4426950408889634f)  // 1/sqrt(32)*log2e

__device__ __forceinline__ f16x2 pkcvt(float a, float b) {
  auto r = __builtin_amdgcn_cvt_pkrtz(a, b);  // v_cvt_pkrtz_f16_f32
  union { decltype(r) in; f16x2 out; } u;
  u.in = r;
  return u.out;
}

__device__ __forceinline__ f16x4 pack4(float4 a) {
  union { f16x4 v; f16x2 h[2]; } u;
  u.h[0] = pkcvt(a.x, a.y);
  u.h[1] = pkcvt(a.z, a.w);
  return u.v;
}

// ---------------------------------------------------------------------------
// Kernel 0: convert Wq|Wk|Wv|Wm (each 256x256 f32) to f16 in k-major tiles:
// dst[m*65536 + kk*8192 + och*32 + (ch&31)] — so a wave's MFMA A-fragment
// load (16 och rows x 32 ch) is one contiguous 1KB block.
// ---------------------------------------------------------------------------
__global__ __launch_bounds__(256)
void cvt_w_kernel(const float* __restrict__ Wq, const float* __restrict__ Wk,
                  const float* __restrict__ Wv, const float* __restrict__ Wm,
                  f16* __restrict__ dst) {
  const int m = blockIdx.x >> 6;  // matrix index (4 x 64 blocks)
  const float* src = (m == 0) ? Wq : (m == 1) ? Wk : (m == 2) ? Wv : Wm;
  const int base = (blockIdx.x & 63) * 1024 + threadIdx.x * 4;  // och*256+ch
  const int och = base >> 8, ch = base & 255;
  float4 a = *(const float4*)(src + base);
  *(f16x4*)(dst + m * 65536 + (ch >> 5) * 8192 + och * 32 + (ch & 31)) =
      pack4(a);
}

// ---------------------------------------------------------------------------
// Kernel 1: fused Q/K/V projection + bias + per-head L2-norm via MFMA.
// Grid (512, 3): blockIdx.y selects tensor; 32 tokens/block, 4 waves,
// wave w computes och 64w..64w+63 (heads 2w,2w+1) x 32 tokens.
// x tile staged to LDS [kk][tok][40] (f16, attn-style conflict-free rows):
// dense 1KB global reads (one token row per wave-instr), pkcvt during stage.
// A-frags from k-major w16: dense 1KB loads. No strided hot loads remain.
// C-layout: col=l16 -> token, row=quad*4+r -> och.
// V store: transposed [32][LSEQ] with column bits 2<->3 swapped (see header).
// ---------------------------------------------------------------------------
#define PKKB 1288  // (32 tok * 40 + 8 pad) f16 per kk block

__global__ __launch_bounds__(256, 2)
void proj_mfma_kernel(const float* __restrict__ xq, const float* __restrict__ xk,
                      const float* __restrict__ xv, const f16* __restrict__ w16,
                      const float* __restrict__ bq, const float* __restrict__ bk,
                      const float* __restrict__ bv,
                      f16* __restrict__ qn, f16* __restrict__ kn,
                      f16* __restrict__ vt) {
  __shared__ f16 xl[8 * PKKB];  // 20608 B
  const int which = blockIdx.y;
  const float* x    = (which == 0) ? xq : (which == 1) ? xk : xv;
  const float* bias = (which == 0) ? bq : (which == 1) ? bk : bv;
  const f16* W      = w16 + which * 65536;
  f16* out          = (which == 0) ? qn : (which == 1) ? kn : vt;
  const float scale = (which == 0) ? QSCALE : 1.0f;
  const bool transposed = (which == 2);

  const int tid = threadIdx.x;
  const int wave = tid >> 6, lane = tid & 63;
  const int quad = lane >> 4, l16 = lane & 15;
  const int tokbase = blockIdx.x * 32;
  const int wbase = wave * 64;

  // ---- stage x tile: 8 rounds, each wave reads ONE full token row (1KB
  // dense), converts, writes f16x4 to LDS. task: tok = flat>>6, c16 = flat&63.
  {
    const int c16 = lane;  // 64 16B-chunks per token
#pragma unroll
    for (int r = 0; r < 8; ++r) {
      const int tok = r * 4 + wave;
      float4 a = *(const float4*)(x + (size_t)(tokbase + tok) * CDIM + c16 * 4);
      *(f16x4*)(&xl[(c16 >> 3) * PKKB + tok * 40 + (c16 & 7) * 4]) = pack4(a);
    }
  }
  __syncthreads();

  f32x4 acc[4][2];  // [m-tile][n-tile]
#pragma unroll
  for (int mt = 0; mt < 4; ++mt)
#pragma unroll
    for (int nt = 0; nt < 2; ++nt) acc[mt][nt] = (f32x4){0.f, 0.f, 0.f, 0.f};

#pragma unroll
  for (int kk = 0; kk < 8; ++kk) {
    f16x8 af[4];
#pragma unroll
    for (int mt = 0; mt < 4; ++mt)
      af[mt] = *(const f16x8*)(W + kk * 8192 + (wbase + mt * 16 + l16) * 32 +
                               quad * 8);
    f16x8 bf0 = *(const f16x8*)(&xl[kk * PKKB + l16 * 40 + quad * 8]);
    f16x8 bf1 = *(const f16x8*)(&xl[kk * PKKB + (16 + l16) * 40 + quad * 8]);
#pragma unroll
    for (int mt = 0; mt < 4; ++mt) {
      acc[mt][0] = __builtin_amdgcn_mfma_f32_16x16x32_f16(af[mt], bf0,
                                                          acc[mt][0], 0, 0, 0);
      acc[mt][1] = __builtin_amdgcn_mfma_f32_16x16x32_f16(af[mt], bf1,
                                                          acc[mt][1], 0, 0, 0);
    }
  }

  // epilogue: bias -> per-head L2 norm (d spans 2 m-tiles x 4 quads) -> store
  const int bt = tokbase >> 10, l0 = tokbase & 1023;
#pragma unroll
  for (int hh = 0; hh < 2; ++hh) {
    const int h = wave * 2 + hh;
    const size_t hb = (size_t)(bt * HEADS + h) * (LSEQ * DHEAD);
    float4 b0 = *(const float4*)(bias + wbase + hh * 32 + quad * 4);
    float4 b1 = *(const float4*)(bias + wbase + hh * 32 + 16 + quad * 4);
#pragma unroll
    for (int nt = 0; nt < 2; ++nt) {
      f32x4 a0 = acc[hh * 2 + 0][nt];
      f32x4 a1 = acc[hh * 2 + 1][nt];
      float v0[4], v1[4];
      v0[0] = a0[0] + b0.x; v0[1] = a0[1] + b0.y;
      v0[2] = a0[2] + b0.z; v0[3] = a0[3] + b0.w;
      v1[0] = a1[0] + b1.x; v1[1] = a1[1] + b1.y;
      v1[2] = a1[2] + b1.z; v1[3] = a1[3] + b1.w;
      float ss = 0.f;
#pragma unroll
      for (int r = 0; r < 4; ++r) ss += v0[r] * v0[r] + v1[r] * v1[r];
      ss += __shfl_xor(ss, 16);
      ss += __shfl_xor(ss, 32);
      const float inv = scale / fmaxf(sqrtf(ss), 1e-12f);
      const int tok_l = l0 + nt * 16 + l16;
      if (!transposed) {
        f16x4 o0, o1;
#pragma unroll
        for (int r = 0; r < 4; ++r) {
          o0[r] = (f16)(v0[r] * inv);
          o1[r] = (f16)(v1[r] * inv);
        }
        *(f16x4*)(out + hb + (size_t)tok_l * DHEAD + quad * 4) = o0;
        *(f16x4*)(out + hb + (size_t)tok_l * DHEAD + 16 + quad * 4) = o1;
      } else {
        // column index with bits 2<->3 swapped (within each 16-token block):
        const int tcol = (tok_l & ~12) | ((tok_l & 4) << 1) | ((tok_l & 8) >> 1);
#pragma unroll
        for (int r = 0; r < 4; ++r) {
          out[hb + (size_t)(quad * 4 + r) * LSEQ + tcol] = (f16)(v0[r] * inv);
          out[hb + (size_t)(16 + quad * 4 + r) * LSEQ + tcol] = (f16)(v1[r] * inv);
        }
      }
    }
  }
}

// ---------------------------------------------------------------------------
// Kernel 2: attention via swapped 32x32x16 MFMA. (unchanged from round 4 —
// verified.) NOTE: xo may alias qn — each block reads exactly the q-rows it
// later writes; ranges disjoint across blocks.
// ---------------------------------------------------------------------------
#define TKROW 40  // padded K row, f16 units (64 rows/tile)
#define TVROW 72  // padded V row, f16 units (32 rows, 64 k-cols/tile)

__global__ __launch_bounds__(256, 4)
void attn_mfma_kernel(const f16* __restrict__ qn,
                      const f16* __restrict__ kn,
                      const f16* __restrict__ vt,
                      f16* __restrict__ xo) {
  __shared__ f16 kl[2][64 * TKROW];  // 2 x 5120B
  __shared__ f16 vl[2][32 * TVROW];  // 2 x 4608B
  const int tid  = threadIdx.x;
  const int wave = tid >> 6, lane = tid & 63;
  const int l32 = lane & 31, hi = lane >> 5;
  // XCD-aware swizzle: all 8 q-chunk blocks of a head land on one XCD's L2.
  const int wid = (blockIdx.x & 7) * 128 + (blockIdx.x >> 3);
  const int bth = wid >> 3;
  const int qbase = ((wid & 7) << 7) + wave * 32;
  const size_t hb = (size_t)bth * (LSEQ * DHEAD);

  const f16* qp = qn + hb + (size_t)(qbase + l32) * DHEAD + hi * 8;
  const f16x8 qf0 = *(const f16x8*)qp;
  const f16x8 qf1 = *(const f16x8*)(qp + 16);

  const int krow_w = wave * 16 + (lane >> 2), kcol = (lane & 3) * 8;
  const int vrow_w = wave * 8 + (lane >> 3), vcol = (lane & 7) * 8;
  const f16* gK = kn + hb + (size_t)krow_w * DHEAD + kcol;  // + t*64*DHEAD
  const f16* gV = vt + hb + (size_t)vrow_w * LSEQ + vcol;   // + t*64
  const int lK = krow_w * TKROW + kcol;
  const int lV = vrow_w * TVROW + vcol;

  f32x16 oacc, z16;
#pragma unroll
  for (int r = 0; r < 16; ++r) { oacc[r] = 0.f; z16[r] = 0.f; }
  float ls0 = 0.f, ls1 = 0.f;

#define EXPPV(s, v0, v1) { \
    union { f16x8 v; f16x2 h[4]; } _q0, _q1; \
    _Pragma("unroll") \
    for (int i = 0; i < 4; ++i) { \
      float e0 = __builtin_amdgcn_exp2f(s[2 * i]); \
      float e1 = __builtin_amdgcn_exp2f(s[2 * i + 1]); \
      ls0 += e0; ls1 += e1; \
      _q0.h[i] = pkcvt(e0, e1); \
      float e2 = __builtin_amdgcn_exp2f(s[8 + 2 * i]); \
      float e3 = __builtin_amdgcn_exp2f(s[9 + 2 * i]); \
      ls0 += e2; ls1 += e3; \
      _q1.h[i] = pkcvt(e2, e3); \
    } \
    oacc = __builtin_amdgcn_mfma_f32_32x32x16_f16(v0, _q0.v, oacc, 0, 0, 0); \
    oacc = __builtin_amdgcn_mfma_f32_32x32x16_f16(v1, _q1.v, oacc, 0, 0, 0); }

  // prologue: stage tile 0, issue tile 1 loads
  f16x8 gk = *(const f16x8*)gK;
  f16x8 gv = *(const f16x8*)gV;
  *(f16x8*)(&kl[0][lK]) = gk;
  *(f16x8*)(&vl[0][lV]) = gv;
  gk = *(const f16x8*)(gK + 64 * DHEAD);
  gv = *(const f16x8*)(gV + 64);
  __syncthreads();

  for (int t = 0; t < 16; ++t) {
    const f16* kb = kl[t & 1];
    const f16* vb = vl[t & 1];
#pragma unroll
    for (int sub = 0; sub < 2; ++sub) {
      f16x8 kf0 = *(const f16x8*)(kb + (sub * 32 + l32) * TKROW + hi * 8);
      f16x8 kf1 = *(const f16x8*)(kb + (sub * 32 + l32) * TKROW + hi * 8 + 16);
      f16x8 vf0 = *(const f16x8*)(vb + l32 * TVROW + sub * 32 + hi * 8);
      f16x8 vf1 = *(const f16x8*)(vb + l32 * TVROW + sub * 32 + hi * 8 + 16);
      f32x16 s = __builtin_amdgcn_mfma_f32_32x32x16_f16(kf0, qf0, z16, 0, 0, 0);
      s = __builtin_amdgcn_mfma_f32_32x32x16_f16(kf1, qf1, s, 0, 0, 0);
      EXPPV(s, vf0, vf1)
    }
    if (t < 15) {
      __syncthreads();  // all waves done reading buf[(t+1)&1] (tile t-1)
      *(f16x8*)(&kl[(t + 1) & 1][lK]) = gk;
      *(f16x8*)(&vl[(t + 1) & 1][lV]) = gv;
      if (t + 1 < 15) {  // issue tile t+2: covered by tile t+1's compute
        gk = *(const f16x8*)(gK + (size_t)(t + 2) * 64 * DHEAD);
        gv = *(const f16x8*)(gV + (t + 2) * 64);
      }
      __syncthreads();  // buf[(t+1)&1] visible
    }
  }
#undef EXPPV

  float lsum = ls0 + ls1;        // own 16 k-rows
  lsum += __shfl_xor(lsum, 32);  // + partner half's 16 k-rows
  const float inv = __builtin_amdgcn_rcpf(lsum);

  f16* op = xo + hb + (size_t)(qbase + l32) * DHEAD + hi * 4;
#pragma unroll
  for (int g = 0; g < 4; ++g) {   // d-base = 8g + 4hi, 4 contiguous d each
    union { f16x4 v; f16x2 h[2]; } o;
    o.h[0] = pkcvt(oacc[4 * g + 0] * inv, oacc[4 * g + 1] * inv);
    o.h[1] = pkcvt(oacc[4 * g + 2] * inv, oacc[4 * g + 3] * inv);
    *(f16x4*)(op + 8 * g) = o.v;
  }
}

// ---------------------------------------------------------------------------
// Kernel 3: out = xatt @ Wm^T + bm + residual, f32 out, via MFMA.
// Round 6: A-frags from k-major Wm16 (dense 1KB, preconverted in cvt_w);
// xatt tile staged to LDS [kk=head][tok][40] via dense per-head 1KB reads
// (tokens are contiguous within a head). 32 tokens/block, grid 512.
// ---------------------------------------------------------------------------
#define OKKB 1288  // (32 tok * 40 + 8 pad) f16 per head block

__global__ __launch_bounds__(256, 2)
void out_proj_mfma_kernel(const f16* __restrict__ xatt,
                          const f16* __restrict__ wm16,
                          const float* __restrict__ bm,
                          const float* __restrict__ resid,
                          float* __restrict__ out) {
  __shared__ f16 xl[8 * OKKB];  // 20608 B
  const int tid = threadIdx.x;
  const int wave = tid >> 6, lane = tid & 63;
  const int quad = lane >> 4, l16 = lane & 15;
  const int tokbase = blockIdx.x * 32;
  const int wbase = wave * 64;
  const int bt = tokbase >> 10, l0 = tokbase & 1023;

  // ---- stage xatt tile: 4 rounds x 256 threads x 16B; per wave one dense
  // 1KB slice of a head's contiguous 2KB token block. No conversion needed.
  {
#pragma unroll
    for (int r = 0; r < 4; ++r) {
      const int flat = r * 256 + tid;           // kk*128 + tok*4 + c8
      const int kk = flat >> 7, rem = flat & 127;
      const int tok = rem >> 2, c8 = rem & 3;
      const f16* gp = xatt + (size_t)(bt * HEADS + kk) * (LSEQ * DHEAD) +
                      (size_t)(l0 + tok) * DHEAD + c8 * 8;
      *(f16x8*)(&xl[kk * OKKB + tok * 40 + c8 * 8]) = *(const f16x8*)gp;
    }
  }
  __syncthreads();

  f32x4 acc[4][2];
#pragma unroll
  for (int mt = 0; mt < 4; ++mt)
#pragma unroll
    for (int nt = 0; nt < 2; ++nt) acc[mt][nt] = (f32x4){0.f, 0.f, 0.f, 0.f};

#pragma unroll
  for (int kk = 0; kk < 8; ++kk) {
    f16x8 af[4];
#pragma unroll
    for (int mt = 0; mt < 4; ++mt)
      af[mt] = *(const f16x8*)(wm16 + kk * 8192 +
                               (wbase + mt * 16 + l16) * 32 + quad * 8);
    f16x8 bf0 = *(const f16x8*)(&xl[kk * OKKB + l16 * 40 + quad * 8]);
    f16x8 bf1 = *(const f16x8*)(&xl[kk * OKKB + (16 + l16) * 40 + quad * 8]);
#pragma unroll
    for (int mt = 0; mt < 4; ++mt) {
      acc[mt][0] = __builtin_amdgcn_mfma_f32_16x16x32_f16(af[mt], bf0,
                                                          acc[mt][0], 0, 0, 0);
      acc[mt][1] = __builtin_amdgcn_mfma_f32_16x16x32_f16(af[mt], bf1,
                                                          acc[mt][1], 0, 0, 0);
    }
  }

#pragma unroll
  for (int mt = 0; mt < 4; ++mt) {
    float4 bv = *(const float4*)(bm + wbase + mt * 16 + quad * 4);
#pragma unroll
    for (int nt = 0; nt < 2; ++nt) {
      const int tok = tokbase + nt * 16 + l16;
      const size_t off = (size_t)tok * CDIM + wbase + mt * 16 + quad * 4;
      float4 rv = *(const float4*)(resid + off);
      float4 o;
      o.x = acc[mt][nt][0] + bv.x + rv.x;
      o.y = acc[mt][nt][1] + bv.y + rv.y;
      o.z = acc[mt][nt][2] + bv.z + rv.z;
      o.w = acc[mt][nt][3] + bv.w + rv.w;
      *(float4*)(out + off) = o;
    }
  }
}

extern "C" void kernel_launch(void* const* d_in, const int* in_sizes, int n_in,
                              void* d_out, int out_size, void* d_ws,
                              size_t ws_size, hipStream_t stream) {
  const float* q  = (const float*)d_in[0];
  const float* k  = (const float*)d_in[1];
  const float* v  = (const float*)d_in[2];
  const float* Wq = (const float*)d_in[3];
  const float* bq = (const float*)d_in[4];
  const float* Wk = (const float*)d_in[5];
  const float* bk = (const float*)d_in[6];
  const float* Wv = (const float*)d_in[7];
  const float* bv = (const float*)d_in[8];
  const float* Wm = (const float*)d_in[9];
  const float* bm = (const float*)d_in[10];
  float* outp = (float*)d_out;

  f16* ws = (f16*)d_ws;
  const size_t TENS = (size_t)NTOK * CDIM;  // 4194304
  f16* qn  = ws;
  f16* kn  = ws + TENS;
  f16* vt  = ws + 2 * TENS;
  f16* w16 = ws + 3 * TENS;  // 4 x 65536 f16 (Wq,Wk,Wv,Wm k-major tiles)
  f16* xa  = qn;             // alias: attn reads its q-rows before writing

  dim3 blk(256);
  cvt_w_kernel<<<dim3(256), blk, 0, stream>>>(Wq, Wk, Wv, Wm, w16);
  proj_mfma_kernel<<<dim3(512, 3), blk, 0, stream>>>(q, k, v, w16, bq, bk, bv,
                                                     qn, kn, vt);
  attn_mfma_kernel<<<dim3(1024), blk, 0, stream>>>(qn, kn, vt, xa);
  out_proj_mfma_kernel<<<dim3(512), blk, 0, stream>>>(xa, w16 + 3 * 65536, bm,
                                                      q, outp);
}